// Round 12
// baseline (102.666 us; speedup 1.0000x reference)
//
#include <hip/hip_runtime.h>

#define D 32
#define CB 256        // rows per coarse bucket
#define CAPC 4608     // bucket capacity: mean 4092 + 8 sigma
#define EPB 8192      // edges per bucket block (512 thr x 16 edges)

// ---- pass 0: zero the bucket counters ----
__global__ void zero_kernel(int* __restrict__ gcount, int nb) {
    int t = threadIdx.x;
    if (t < nb) gcount[t] = 0;
}

// ---- pass 1: partition edges into 391 coarse buckets (row>>8) ----
// key = (r & 255) << 17 | col   (requires N <= 131072)
__global__ __launch_bounds__(512) void bucket_kernel(
        const int* __restrict__ row, const int* __restrict__ col,
        const float* __restrict__ val, int* __restrict__ gcount,
        int2* __restrict__ bkv, int E, int NBUCK) {
    __shared__ int hist[512];
    __shared__ int base[512];
    int t = threadIdx.x;
    if (t < NBUCK) hist[t] = 0;
    __syncthreads();
    long e0 = (long)blockIdx.x * EPB;
    int rr[16]; unsigned kk[16]; float vv[16];
#pragma unroll
    for (int u = 0; u < 4; ++u) {
        long e = e0 + (long)t * 4 + (long)u * 2048;
        if (e + 3 < E) {
            int4   r4 = *reinterpret_cast<const int4*>(&row[e]);
            int4   c4 = *reinterpret_cast<const int4*>(&col[e]);
            float4 v4 = *reinterpret_cast<const float4*>(&val[e]);
            rr[4*u+0] = r4.x; rr[4*u+1] = r4.y; rr[4*u+2] = r4.z; rr[4*u+3] = r4.w;
            kk[4*u+0] = ((unsigned)(r4.x & 255) << 17) | (unsigned)c4.x;
            kk[4*u+1] = ((unsigned)(r4.y & 255) << 17) | (unsigned)c4.y;
            kk[4*u+2] = ((unsigned)(r4.z & 255) << 17) | (unsigned)c4.z;
            kk[4*u+3] = ((unsigned)(r4.w & 255) << 17) | (unsigned)c4.w;
            vv[4*u+0] = v4.x; vv[4*u+1] = v4.y; vv[4*u+2] = v4.z; vv[4*u+3] = v4.w;
        } else {
#pragma unroll
            for (int k = 0; k < 4; ++k) {
                long ee = e + k;
                bool ok = ee < E;
                int r = ok ? row[ee] : -1;
                rr[4*u+k] = r;
                kk[4*u+k] = ok ? (((unsigned)(r & 255) << 17) | (unsigned)col[ee]) : 0u;
                vv[4*u+k] = ok ? val[ee] : 0.0f;
            }
        }
    }
#pragma unroll
    for (int i = 0; i < 16; ++i)              // A: LDS histogram from registers
        if (rr[i] >= 0) atomicAdd(&hist[rr[i] >> 8], 1);
    __syncthreads();
    if (t < NBUCK) {                          // B: one reservation atomic per (block,bucket)
        int h = hist[t];
        base[t] = h ? atomicAdd(&gcount[t], h) : 0;
        hist[t] = 0;
    }
    __syncthreads();
#pragma unroll
    for (int i = 0; i < 16; ++i) {            // C: scatter (~21-edge contiguous runs)
        if (rr[i] >= 0) {
            int b = rr[i] >> 8;
            int rank = atomicAdd(&hist[b], 1);
            int pos = base[b] + rank;
            if (pos < CAPC)
                bkv[(long)b * CAPC + pos] = make_int2((int)kk[i], __float_as_int(vv[i]));
        }
    }
}

// ---- pass 2 (fused): per-bucket LDS counting sort (in place) + deg->dis + CSR
//      + Y = dis * (X @ W^T) for the bucket's own 256 rows.
__global__ __launch_bounds__(512) void sortdisxw_kernel(
        const int* __restrict__ gcount, int2* __restrict__ bkv,
        const float* __restrict__ X, const float* __restrict__ W,
        int* __restrict__ rowstart, int* __restrict__ rowcnt,
        float* __restrict__ dis, float* __restrict__ Y, int N) {
    __shared__ int2 srt[CAPC];                // 36.9 KB
    __shared__ int hist[CB], rs[CB], cur[CB];
    __shared__ float degl[CB], sdis[CB];
    __shared__ float sWt[32][33];             // 4.2 KB
    int t = threadIdx.x, b = blockIdx.x;
    for (int k = t; k < 1024; k += 512) sWt[k & 31][k >> 5] = W[k];
    if (t < CB) { hist[t] = 0; degl[t] = 0.0f; }
    __syncthreads();
    int n = gcount[b];
    if (n > CAPC) n = CAPC;
    long base = (long)b * CAPC;
    int2 kv[9]; bool ok[9];
#pragma unroll
    for (int u = 0; u < 9; ++u) {             // register-staged single read
        int idx = t + u * 512;
        ok[u] = idx < n;
        kv[u] = ok[u] ? bkv[base + idx] : make_int2(0, 0);
    }
#pragma unroll
    for (int u = 0; u < 9; ++u) {
        if (ok[u]) {
            int lr = ((unsigned)kv[u].x) >> 17;
            atomicAdd(&hist[lr], 1);
            atomicAdd(&degl[lr], __int_as_float(kv[u].y));
        }
    }
    __syncthreads();
    if (t < CB) rs[t] = hist[t];
    __syncthreads();
    for (int o = 1; o < CB; o <<= 1) {        // Hillis-Steele inclusive scan
        int v = (t < CB && t >= o) ? rs[t - o] : 0;
        __syncthreads();
        if (t < CB) rs[t] += v;
        __syncthreads();
    }
    if (t < CB) {
        int excl = rs[t] - hist[t];
        cur[t] = excl;
        float dg = degl[t];
        float di = dg > 0.0f ? rsqrtf(dg) : 0.0f;
        sdis[t] = di;
        int gr = (b << 8) + t;
        if (gr < N) {
            rowstart[gr] = (int)(base + excl);
            rowcnt[gr] = hist[t];
            dis[gr] = di;
        }
    }
    __syncthreads();
#pragma unroll
    for (int u = 0; u < 9; ++u) {             // scatter-sort into LDS
        if (ok[u]) {
            unsigned key = (unsigned)kv[u].x;
            int pos = atomicAdd(&cur[key >> 17], 1);
            srt[pos] = make_int2((int)(key & 0x1FFFF), kv[u].y);
        }
    }
    // fused xw for own 256 rows: Y[gr] = sdis[r] * (X[gr] @ W^T)
    {
        int g = t >> 5, c = t & 31;           // 16 groups of 32 lanes
#pragma unroll
        for (int it = 0; it < 16; ++it) {
            int r = it * 16 + g;
            int gr = (b << 8) + r;
            float x = (gr < N) ? X[(long)gr * D + c] : 0.0f;
            float acc = 0.0f;
#pragma unroll
            for (int i = 0; i < 32; ++i)
                acc = fmaf(__shfl(x, i, 32), sWt[i][c], acc);
            if (gr < N) Y[(long)gr * D + c] = acc * sdis[r];
        }
    }
    __syncthreads();
#pragma unroll
    for (int u = 0; u < 9; ++u) {             // coalesced in-place write-back
        int idx = t + u * 512;
        if (idx < n) bkv[base + idx] = srt[idx];
    }
}

// ---- pass 3: aggregation, phase-split for MLP. Wave owns 4 rows; 24-edge
//      predicated fast path (12 kv + 12 Y loads all in flight), rare fallback.
__global__ __launch_bounds__(256) void agg_kernel(
        const int* __restrict__ rowstart, const int* __restrict__ rowcnt,
        const int2* __restrict__ bkv, const float* __restrict__ dis,
        const float* __restrict__ Y, float* __restrict__ out, int N) {
    int t = threadIdx.x;
    int wv = t >> 6, lane = t & 63;
    int sub = lane >> 3;        // edge slot 0..7
    int dl = lane & 7;          // float4 feature chunk 0..7
    int r0 = blockIdx.x * 16 + wv * 4;

    int st[4], cn[4];
    int2 kv[4][3];
    float4 yv[4][3];
    float4 acc[4];
#pragma unroll
    for (int m = 0; m < 4; ++m) {
        int gr = r0 + m;
        bool v = gr < N;
        st[m] = v ? rowstart[gr] : 0;
        cn[m] = v ? rowcnt[gr] : 0;
        acc[m] = make_float4(0.f, 0.f, 0.f, 0.f);
    }
    // phase 1: issue all 12 kv loads (clamped safe addresses)
#pragma unroll
    for (int m = 0; m < 4; ++m) {
        int cm1 = cn[m] > 0 ? cn[m] - 1 : 0;
#pragma unroll
        for (int b = 0; b < 3; ++b) {
            int i = b * 8 + sub;
            kv[m][b] = bkv[st[m] + (i < cn[m] ? i : cm1)];
        }
    }
    // phase 2: issue all 12 dependent Y gathers (col masked for safety)
#pragma unroll
    for (int m = 0; m < 4; ++m)
#pragma unroll
        for (int b = 0; b < 3; ++b)
            yv[m][b] = *reinterpret_cast<const float4*>(
                &Y[(long)(kv[m][b].x & 0x1FFFF) * D + dl * 4]);
    // phase 3: predicated FMAs
#pragma unroll
    for (int m = 0; m < 4; ++m) {
#pragma unroll
        for (int b = 0; b < 3; ++b) {
            int i = b * 8 + sub;
            float v = (i < cn[m]) ? __int_as_float(kv[m][b].y) : 0.0f;
            acc[m].x = fmaf(v, yv[m][b].x, acc[m].x);
            acc[m].y = fmaf(v, yv[m][b].y, acc[m].y);
            acc[m].z = fmaf(v, yv[m][b].z, acc[m].z);
            acc[m].w = fmaf(v, yv[m][b].w, acc[m].w);
        }
    }
    // fallback: rows with cnt > 24 (~2% of rows)
#pragma unroll
    for (int m = 0; m < 4; ++m) {
        for (int j = 24 + sub; j < cn[m]; j += 8) {
            int2 k2 = bkv[st[m] + j];
            const float4 y2 = *reinterpret_cast<const float4*>(
                &Y[(long)(k2.x & 0x1FFFF) * D + dl * 4]);
            float v = __int_as_float(k2.y);
            acc[m].x = fmaf(v, y2.x, acc[m].x);
            acc[m].y = fmaf(v, y2.y, acc[m].y);
            acc[m].z = fmaf(v, y2.z, acc[m].z);
            acc[m].w = fmaf(v, y2.w, acc[m].w);
        }
    }
    // reduce across 8 edge slots + store
#pragma unroll
    for (int m = 0; m < 4; ++m) {
#pragma unroll
        for (int s = 8; s <= 32; s <<= 1) {
            acc[m].x += __shfl_xor(acc[m].x, s, 64);
            acc[m].y += __shfl_xor(acc[m].y, s, 64);
            acc[m].z += __shfl_xor(acc[m].z, s, 64);
            acc[m].w += __shfl_xor(acc[m].w, s, 64);
        }
        int gr = r0 + m;
        if (gr < N && sub == 0) {
            float sc = dis[gr];
            *reinterpret_cast<float4*>(&out[(long)gr * D + dl * 4]) =
                make_float4(sc * acc[m].x, sc * acc[m].y, sc * acc[m].z, sc * acc[m].w);
        }
    }
}

extern "C" void kernel_launch(void* const* d_in, const int* in_sizes, int n_in,
                              void* d_out, int out_size, void* d_ws, size_t ws_size,
                              hipStream_t stream) {
    const int*   row = (const int*)d_in[0];
    const int*   col = (const int*)d_in[1];
    const float* val = (const float*)d_in[2];
    const float* X   = (const float*)d_in[3];
    const float* W   = (const float*)d_in[4];
    const int E = in_sizes[0];
    const int N = in_sizes[3] / D;
    float* out = (float*)d_out;

    const int NBUCK = (N + CB - 1) / CB;          // 391

    char* w = (char*)d_ws;
    int*   gcount   = (int*)w;                                     // 4096 ints
    float* dis      = (float*)(w + 16384);                         // N
    int*   rowstart = (int*)(w + 16384 + (size_t)N * 4);           // N
    int*   rowcnt   = (int*)(w + 16384 + (size_t)N * 8);           // N
    float* Y        = (float*)(w + 16384 + (size_t)N * 12);        // N*D
    int2*  bkv      = (int2*)(w + 16384 + (size_t)N * 12 + (size_t)N * D * 4);

    zero_kernel<<<1, 512, 0, stream>>>(gcount, NBUCK);
    bucket_kernel<<<(E + EPB - 1) / EPB, 512, 0, stream>>>(
        row, col, val, gcount, bkv, E, NBUCK);
    sortdisxw_kernel<<<NBUCK, 512, 0, stream>>>(gcount, bkv, X, W,
                                                rowstart, rowcnt, dis, Y, N);
    agg_kernel<<<(N + 15) / 16, 256, 0, stream>>>(rowstart, rowcnt, bkv, dis, Y, out, N);
}

// Round 13
// 93.514 us; speedup vs baseline: 1.0979x; 1.0979x over previous
//
#include <hip/hip_runtime.h>

#define D 32
#define CB 256        // rows per coarse bucket
#define CAPC 4608     // bucket capacity: mean 4092 + 8 sigma
#define EPB 8192      // edges per bucket block (512 thr x 16 edges)

// ---- pass 0: zero the bucket counters ----
__global__ void zero_kernel(int* __restrict__ gcount, int nb) {
    int t = threadIdx.x;
    if (t < nb) gcount[t] = 0;
}

// ---- pass 1: partition edges into 391 coarse buckets (row>>8) ----
// key = (r & 255) << 17 | col   (requires N <= 131072)
__global__ __launch_bounds__(512) void bucket_kernel(
        const int* __restrict__ row, const int* __restrict__ col,
        const float* __restrict__ val, int* __restrict__ gcount,
        int2* __restrict__ bkv, int E, int NBUCK) {
    __shared__ int hist[512];
    __shared__ int base[512];
    int t = threadIdx.x;
    if (t < NBUCK) hist[t] = 0;
    __syncthreads();
    long e0 = (long)blockIdx.x * EPB;
    int rr[16]; unsigned kk[16]; float vv[16];
#pragma unroll
    for (int u = 0; u < 4; ++u) {
        long e = e0 + (long)t * 4 + (long)u * 2048;
        if (e + 3 < E) {
            int4   r4 = *reinterpret_cast<const int4*>(&row[e]);
            int4   c4 = *reinterpret_cast<const int4*>(&col[e]);
            float4 v4 = *reinterpret_cast<const float4*>(&val[e]);
            rr[4*u+0] = r4.x; rr[4*u+1] = r4.y; rr[4*u+2] = r4.z; rr[4*u+3] = r4.w;
            kk[4*u+0] = ((unsigned)(r4.x & 255) << 17) | (unsigned)c4.x;
            kk[4*u+1] = ((unsigned)(r4.y & 255) << 17) | (unsigned)c4.y;
            kk[4*u+2] = ((unsigned)(r4.z & 255) << 17) | (unsigned)c4.z;
            kk[4*u+3] = ((unsigned)(r4.w & 255) << 17) | (unsigned)c4.w;
            vv[4*u+0] = v4.x; vv[4*u+1] = v4.y; vv[4*u+2] = v4.z; vv[4*u+3] = v4.w;
        } else {
#pragma unroll
            for (int k = 0; k < 4; ++k) {
                long ee = e + k;
                bool ok = ee < E;
                int r = ok ? row[ee] : -1;
                rr[4*u+k] = r;
                kk[4*u+k] = ok ? (((unsigned)(r & 255) << 17) | (unsigned)col[ee]) : 0u;
                vv[4*u+k] = ok ? val[ee] : 0.0f;
            }
        }
    }
#pragma unroll
    for (int i = 0; i < 16; ++i)              // A: LDS histogram from registers
        if (rr[i] >= 0) atomicAdd(&hist[rr[i] >> 8], 1);
    __syncthreads();
    if (t < NBUCK) {                          // B: one reservation atomic per (block,bucket)
        int h = hist[t];
        base[t] = h ? atomicAdd(&gcount[t], h) : 0;
        hist[t] = 0;
    }
    __syncthreads();
#pragma unroll
    for (int i = 0; i < 16; ++i) {            // C: scatter (~21-edge contiguous runs)
        if (rr[i] >= 0) {
            int b = rr[i] >> 8;
            int rank = atomicAdd(&hist[b], 1);
            int pos = base[b] + rank;
            if (pos < CAPC)
                bkv[(long)b * CAPC + pos] = make_int2((int)kk[i], __float_as_int(vv[i]));
        }
    }
}

// ---- pass 2: per-bucket degrees -> dis, then LDS-staged xw for own 256 rows ----
__global__ __launch_bounds__(512) void degdisxw_kernel(
        const int* __restrict__ gcount, const int2* __restrict__ bkv,
        const float* __restrict__ X, const float* __restrict__ W,
        float* __restrict__ dis, float* __restrict__ Y, int N) {
    __shared__ float sX[CB][D + 1];           // 33.8 KB
    __shared__ float sWt[32][33];             // 4.2 KB
    __shared__ float degl[CB], sdis[CB];
    int t = threadIdx.x, b = blockIdx.x;
    int n = gcount[b];
    if (n > CAPC) n = CAPC;
    long base = (long)b * CAPC;
    // issue bkv reads into registers (overlaps with LDS staging below)
    int2 kv9[9]; bool ok9[9];
#pragma unroll
    for (int u = 0; u < 9; ++u) {
        int idx = t + u * 512;
        ok9[u] = idx < n;
        kv9[u] = ok9[u] ? bkv[base + idx] : make_int2(0, 0);
    }
    for (int k = t; k < 1024; k += 512) sWt[k & 31][k >> 5] = W[k];
    if (t < CB) { degl[t] = 0.0f; }
    for (int k = t; k < CB * D; k += 512) {   // stage X tile, coalesced
        int r = k >> 5, c = k & 31;
        int gr = (b << 8) + r;
        sX[r][c] = (gr < N) ? X[(long)gr * D + c] : 0.0f;
    }
    __syncthreads();
#pragma unroll
    for (int u = 0; u < 9; ++u)
        if (ok9[u])
            atomicAdd(&degl[((unsigned)kv9[u].x) >> 17], __int_as_float(kv9[u].y));
    __syncthreads();
    if (t < CB) {
        float dg = degl[t];
        float di = dg > 0.0f ? rsqrtf(dg) : 0.0f;
        sdis[t] = di;
        int gr = (b << 8) + t;
        if (gr < N) dis[gr] = di;
    }
    __syncthreads();
    int g = t >> 5, c = t & 31;               // 16 groups of 32 lanes
#pragma unroll
    for (int it = 0; it < 16; ++it) {
        int r = it * 16 + g;
        int gr = (b << 8) + r;
        float acc = 0.0f;
#pragma unroll
        for (int i = 0; i < 32; ++i)
            acc = fmaf(sX[r][i], sWt[i][c], acc);   // sX broadcast, sWt conflict-free
        if (gr < N) Y[(long)gr * D + c] = acc * sdis[r];
    }
}

// ---- pass 3 (fused): sort bucket into LDS srt, aggregate from LDS with
//      phase-split Y gathers (24-edge fast path), single coalesced out write.
__global__ __launch_bounds__(512) void sortagg_kernel(
        const int* __restrict__ gcount, const int2* __restrict__ bkv,
        const float* __restrict__ dis, const float* __restrict__ Y,
        float* __restrict__ out, int N) {
    __shared__ int2 srt[CAPC];                // 36.9 KB
    __shared__ int hist[CB], rs[CB], cur[CB];
    __shared__ float sdis[CB];
    int t = threadIdx.x, b = blockIdx.x;
    if (t < CB) {
        hist[t] = 0;
        int gr = (b << 8) + t;
        sdis[t] = (gr < N) ? dis[gr] : 0.0f;
    }
    __syncthreads();
    int n = gcount[b];
    if (n > CAPC) n = CAPC;
    long base = (long)b * CAPC;
    int2 kv9[9]; bool ok9[9];
#pragma unroll
    for (int u = 0; u < 9; ++u) {             // register-staged single read
        int idx = t + u * 512;
        ok9[u] = idx < n;
        kv9[u] = ok9[u] ? bkv[base + idx] : make_int2(0, 0);
    }
#pragma unroll
    for (int u = 0; u < 9; ++u)
        if (ok9[u]) atomicAdd(&hist[((unsigned)kv9[u].x) >> 17], 1);
    __syncthreads();
    if (t < CB) rs[t] = hist[t];
    __syncthreads();
    for (int o = 1; o < CB; o <<= 1) {        // Hillis-Steele inclusive scan
        int v = (t < CB && t >= o) ? rs[t - o] : 0;
        __syncthreads();
        if (t < CB) rs[t] += v;
        __syncthreads();
    }
    if (t < CB) cur[t] = rs[t] - hist[t];     // exclusive start
    __syncthreads();
#pragma unroll
    for (int u = 0; u < 9; ++u) {             // scatter-sort into LDS
        if (ok9[u]) {
            unsigned key = (unsigned)kv9[u].x;
            int pos = atomicAdd(&cur[key >> 17], 1);
            srt[pos] = make_int2((int)(key & 0x1FFFF), kv9[u].y);
        }
    }
    __syncthreads();
    // ---- aggregation from LDS srt ----
    int wv = t >> 6, lane = t & 63;
    int sub = lane >> 3;        // edge slot 0..7
    int dl = lane & 7;          // float4 feature chunk 0..7
    int nm1 = n > 0 ? n - 1 : 0;
    for (int g2 = 0; g2 < 8; ++g2) {
        int rb4 = wv * 32 + g2 * 4;
        int st[4], cn[4];
        int2 kvf[4][3];
        float4 yv[4][3], acc[4];
#pragma unroll
        for (int m = 0; m < 4; ++m) {
            int r = rb4 + m;
            st[m] = rs[r] - hist[r];
            cn[m] = hist[r];
            acc[m] = make_float4(0.f, 0.f, 0.f, 0.f);
        }
#pragma unroll
        for (int m = 0; m < 4; ++m) {         // phase 1: 12 LDS kv reads (clamped)
#pragma unroll
            for (int bb = 0; bb < 3; ++bb) {
                int i = bb * 8 + sub;
                int idx = st[m] + (i < cn[m] ? i : (cn[m] > 0 ? cn[m] - 1 : 0));
                kvf[m][bb] = srt[idx <= nm1 ? idx : nm1];
            }
        }
#pragma unroll
        for (int m = 0; m < 4; ++m)           // phase 2: 12 Y gathers in flight
#pragma unroll
            for (int bb = 0; bb < 3; ++bb) {
                int cc = kvf[m][bb].x & 0x1FFFF;
                cc = cc < N ? cc : 0;
                yv[m][bb] = *reinterpret_cast<const float4*>(&Y[(long)cc * D + dl * 4]);
            }
#pragma unroll
        for (int m = 0; m < 4; ++m) {         // phase 3: predicated FMAs
#pragma unroll
            for (int bb = 0; bb < 3; ++bb) {
                int i = bb * 8 + sub;
                float v = (i < cn[m]) ? __int_as_float(kvf[m][bb].y) : 0.0f;
                acc[m].x = fmaf(v, yv[m][bb].x, acc[m].x);
                acc[m].y = fmaf(v, yv[m][bb].y, acc[m].y);
                acc[m].z = fmaf(v, yv[m][bb].z, acc[m].z);
                acc[m].w = fmaf(v, yv[m][bb].w, acc[m].w);
            }
        }
#pragma unroll
        for (int m = 0; m < 4; ++m) {         // fallback: cnt > 24 (~2% of rows)
            for (int j = 24 + sub; j < cn[m]; j += 8) {
                int2 k2 = srt[st[m] + j];
                int cc = k2.x & 0x1FFFF;
                cc = cc < N ? cc : 0;
                const float4 y2 = *reinterpret_cast<const float4*>(&Y[(long)cc * D + dl * 4]);
                float v = __int_as_float(k2.y);
                acc[m].x = fmaf(v, y2.x, acc[m].x);
                acc[m].y = fmaf(v, y2.y, acc[m].y);
                acc[m].z = fmaf(v, y2.z, acc[m].z);
                acc[m].w = fmaf(v, y2.w, acc[m].w);
            }
        }
#pragma unroll
        for (int m = 0; m < 4; ++m) {         // reduce across 8 edge slots + store
#pragma unroll
            for (int s = 8; s <= 32; s <<= 1) {
                acc[m].x += __shfl_xor(acc[m].x, s, 64);
                acc[m].y += __shfl_xor(acc[m].y, s, 64);
                acc[m].z += __shfl_xor(acc[m].z, s, 64);
                acc[m].w += __shfl_xor(acc[m].w, s, 64);
            }
            int r = rb4 + m;
            int gr = (b << 8) + r;
            if (gr < N && sub == 0) {
                float sc = sdis[r];
                *reinterpret_cast<float4*>(&out[(long)gr * D + dl * 4]) =
                    make_float4(sc * acc[m].x, sc * acc[m].y, sc * acc[m].z, sc * acc[m].w);
            }
        }
    }
}

extern "C" void kernel_launch(void* const* d_in, const int* in_sizes, int n_in,
                              void* d_out, int out_size, void* d_ws, size_t ws_size,
                              hipStream_t stream) {
    const int*   row = (const int*)d_in[0];
    const int*   col = (const int*)d_in[1];
    const float* val = (const float*)d_in[2];
    const float* X   = (const float*)d_in[3];
    const float* W   = (const float*)d_in[4];
    const int E = in_sizes[0];
    const int N = in_sizes[3] / D;
    float* out = (float*)d_out;

    const int NBUCK = (N + CB - 1) / CB;          // 391

    char* w = (char*)d_ws;
    int*   gcount = (int*)w;                                   // 4096 ints
    float* dis    = (float*)(w + 16384);                       // N
    float* Y      = (float*)(w + 16384 + (size_t)N * 4);       // N*D
    int2*  bkv    = (int2*)(w + 16384 + (size_t)N * 4 + (size_t)N * D * 4);

    zero_kernel<<<1, 512, 0, stream>>>(gcount, NBUCK);
    bucket_kernel<<<(E + EPB - 1) / EPB, 512, 0, stream>>>(
        row, col, val, gcount, bkv, E, NBUCK);
    degdisxw_kernel<<<NBUCK, 512, 0, stream>>>(gcount, bkv, X, W, dis, Y, N);
    sortagg_kernel<<<NBUCK, 512, 0, stream>>>(gcount, bkv, dis, Y, out, N);
}